// Round 11
// baseline (1326.559 us; speedup 1.0000x reference)
//
#include <hip/hip_runtime.h>
#include <math.h>

typedef unsigned short u16;
typedef short s16x8 __attribute__((ext_vector_type(8)));
typedef float f32x4 __attribute__((ext_vector_type(4)));

#define GLOAD16(gp, lp)                                                        \
  __builtin_amdgcn_global_load_lds(                                            \
      (const __attribute__((address_space(1))) void*)(gp),                     \
      (__attribute__((address_space(3))) void*)(lp), 16, 0, 0)

__device__ __forceinline__ u16 f2bf(float f) {
  union { float f; unsigned u; } v; v.f = f;
  unsigned r = v.u + 0x7fffu + ((v.u >> 16) & 1u);  // RNE
  return (u16)(r >> 16);
}

// ------- kernel A: transpose+cvt (y=0..5) + x cvt (y=6).
// mats 0-3 (g/u) write into interleaved GU: row = (f>>4)*32 + t*16 + (f&15).
// mats 4,5 plain transpose. y=6: x fp32->bf16 flat copy (blocks 0..8191).
__global__ __launch_bounds__(256) void prep_kernel(
    const float* __restrict__ in0, const float* __restrict__ in1,
    const float* __restrict__ in2, const float* __restrict__ in3,
    const float* __restrict__ in4, const float* __restrict__ in5,
    const float* __restrict__ xin,
    u16* __restrict__ o01, u16* __restrict__ o23,
    u16* __restrict__ o4, u16* __restrict__ o5, u16* __restrict__ xout) {
  const int mat = blockIdx.y;
  const int t = threadIdx.x;
  if (mat == 6) {  // x conversion: 8192 blocks x 2048 elems
    if (blockIdx.x >= 8192) return;
    size_t i = ((size_t)blockIdx.x * 256 + t) * 8;
    float4 a = *(const float4*)(xin + i);
    float4 b = *(const float4*)(xin + i + 4);
    s16x8 v;
    v[0] = (short)f2bf(a.x); v[1] = (short)f2bf(a.y);
    v[2] = (short)f2bf(a.z); v[3] = (short)f2bf(a.w);
    v[4] = (short)f2bf(b.x); v[5] = (short)f2bf(b.y);
    v[6] = (short)f2bf(b.z); v[7] = (short)f2bf(b.w);
    *(s16x8*)(xout + i) = v;
    return;
  }
  __shared__ float s[64 * 65];
  const float* in; u16* out;
  switch (mat) {
    case 0: in = in0; out = o01; break;
    case 1: in = in1; out = o01; break;
    case 2: in = in2; out = o23; break;
    case 3: in = in3; out = o23; break;
    case 4: in = in4; out = o4; break;
    default: in = in5; out = o5; break;
  }
  const int R = (mat < 4) ? 4096 : 11008;   // input rows = output stride
  const int C = (mat < 4) ? 11008 : 4096;   // input cols
  const int nTc = C >> 6;
  const int tr = blockIdx.x / nTc, tc = blockIdx.x - tr * nTc;
  const int r0 = tr << 6, c0 = tc << 6;
#pragma unroll
  for (int p = 0; p < 4; ++p) {
    const int lr = p * 16 + (t >> 4);
    const int lc = (t & 15) * 4;
    float4 v = *(const float4*)(in + (size_t)(r0 + lr) * C + (c0 + lc));
    float* sp = &s[lr * 65 + lc];
    sp[0] = v.x; sp[1] = v.y; sp[2] = v.z; sp[3] = v.w;
  }
  __syncthreads();
#pragma unroll
  for (int q = 0; q < 2; ++q) {
    const int oc = q * 32 + (t >> 3);
    const int orr = (t & 7) * 8;
    s16x8 v;
#pragma unroll
    for (int i = 0; i < 8; ++i) v[i] = (short)f2bf(s[(orr + i) * 65 + oc]);
    const int f = c0 + oc;
    size_t orow;
    if (mat < 4) orow = (size_t)((f >> 4) << 5) + ((mat & 1) << 4) + (f & 15);
    else         orow = (size_t)f;
    *(s16x8*)(out + orow * R + (r0 + orr)) = v;
  }
}

// ======== 8-phase 256x256 GEMM, frag-once schedule (R5 core, verified) ======
#define SBAR() __builtin_amdgcn_s_barrier()
#define LGKM0() asm volatile("s_waitcnt lgkmcnt(0)")
#define LGKM8() asm volatile("s_waitcnt lgkmcnt(8)")
#define VMCNT6() asm volatile("s_waitcnt vmcnt(6)")
#define VMCNT0() asm volatile("s_waitcnt vmcnt(0)")

// ---------------- persistent gate+up GEMM + silu fusion ----------------
// Static XCD-aligned mapping (16 same-c blocks on one XCD share B panels).
// NEW: paced walk — every 8 K-tiles the 8 blocks sharing a (c,side) B stream
// sync on a device counter (bounded spin, deadlock-free) so the shared panel
// window stays L2-resident (attacks the measured 2.4x B over-fetch).
__global__ __launch_bounds__(512, 1) void gemm_gateup_persist(
    const u16* __restrict__ A, const u16* __restrict__ Bl,
    const u16* __restrict__ Bv, const int* __restrict__ tt,
    u16* __restrict__ H, int* __restrict__ pacecnt) {
  __shared__ u16 sA[2][2][128][64];
  __shared__ u16 sB[2][2][128][64];

  const int bid = blockIdx.x;
  const int c = ((bid >> 7) << 3) | (bid & 7);
  const int mT = (bid >> 3) & 15;
  const int ntiles = (c < 6) ? 6 : 5;
  const int FK = ntiles * 64;

  const int t = threadIdx.x;
  const int lane = t & 63;
  const int rlo = lane & 15;
  const int hi = lane >> 4;
  const int wn = (t >> 6) & 3;
  const int wm = (t >> 8) & 1;

  const int side = tt[mT << 8];
  const u16* B = side ? Bl : Bv;
  const int gid = c + 16 * side;  // pace group: 8 blocks share (c, side)

  const int rowq = t >> 3;
  const int gsw = ((t & 7) ^ (rowq & 7)) << 4;
  const char* srcA = (const char*)A + (size_t)(mT * 256 + rowq) * 8192 + gsw;
  const char* srcB0 = (const char*)B + ((size_t)(c * 256) + rowq) * 8192 + gsw;
  char* ldsA = (char*)&sA[0][0][0][0];
  char* ldsB = (char*)&sB[0][0][0][0];
  const int woff = (t & 448) << 4;

#define PSTG_A(d, h, q)                                                        \
  do {                                                                         \
    const char* _pa = srcA + ((q) & 63) * 128;                                 \
    GLOAD16(_pa + (size_t)((h) * 128) * 8192,                                  \
            ldsA + (d) * 32768 + (h) * 16384 + woff);                          \
    GLOAD16(_pa + (size_t)((h) * 128 + 64) * 8192,                             \
            ldsA + (d) * 32768 + (h) * 16384 + 8192 + woff);                   \
  } while (0)
#define PSTG_B(d, h, q)                                                        \
  do {                                                                         \
    const char* _pb = srcB0 + (size_t)((q) >> 6) * 33554432 +                  \
                      (size_t)((h) * 128) * 8192 + ((q) & 63) * 128;           \
    GLOAD16(_pb, ldsB + (d) * 32768 + (h) * 16384 + woff);                     \
    GLOAD16(_pb + (size_t)64 * 8192,                                           \
            ldsB + (d) * 32768 + (h) * 16384 + 8192 + woff);                   \
  } while (0)

  const int cxa = (hi ^ (rlo & 7)) << 4;
  const int cxb = ((4 + hi) ^ (rlo & 7)) << 4;
  const int arow = (wm * 64 + rlo) * 128;
  const int brow = (wn * 32 + rlo) * 128;

  s16x8 af[4][2], bf[2][2][2];  // bf[nh-set][gi][ks] resident across P1..P4
  f32x4 acc[8][4];
  const f32x4 z = {0.f, 0.f, 0.f, 0.f};
#pragma unroll
  for (int i = 0; i < 8; ++i)
#pragma unroll
    for (int j = 0; j < 4; ++j) acc[i][j] = z;

#define LDA(d, mh)                                                             \
  do {                                                                         \
    _Pragma("unroll") for (int fi = 0; fi < 4; ++fi) {                         \
      const char* p = ldsA + (d) * 32768 + (mh) * 16384 + arow + fi * 2048;    \
      af[fi][0] = *(const s16x8*)(p + cxa);                                    \
      af[fi][1] = *(const s16x8*)(p + cxb);                                    \
    }                                                                          \
  } while (0)
#define LDBS(bi, d, nh)                                                        \
  do {                                                                         \
    _Pragma("unroll") for (int gi = 0; gi < 2; ++gi) {                         \
      const char* p = ldsB + (d) * 32768 + (nh) * 16384 + brow + gi * 2048;    \
      bf[bi][gi][0] = *(const s16x8*)(p + cxa);                                \
      bf[bi][gi][1] = *(const s16x8*)(p + cxb);                                \
    }                                                                          \
  } while (0)
#define MFMA16(mh, nh)                                                         \
  do {                                                                         \
    __builtin_amdgcn_s_setprio(1);                                             \
    _Pragma("unroll") for (int fi = 0; fi < 4; ++fi)                           \
        _Pragma("unroll") for (int gi = 0; gi < 2; ++gi) {                     \
      acc[(mh)*4 + fi][(nh)*2 + gi] = __builtin_amdgcn_mfma_f32_16x16x32_bf16( \
          af[fi][0], bf[nh][gi][0], acc[(mh)*4 + fi][(nh)*2 + gi], 0, 0, 0);   \
      acc[(mh)*4 + fi][(nh)*2 + gi] = __builtin_amdgcn_mfma_f32_16x16x32_bf16( \
          af[fi][1], bf[nh][gi][1], acc[(mh)*4 + fi][(nh)*2 + gi], 0, 0, 0);   \
    }                                                                          \
    __builtin_amdgcn_s_setprio(0);                                             \
  } while (0)

#define GU_EPI(nTv)                                                            \
  do {                                                                         \
    const int _nT = (nTv);                                                     \
    _Pragma("unroll") for (int mh = 0; mh < 2; ++mh)                           \
        _Pragma("unroll") for (int fi = 0; fi < 4; ++fi) {                     \
      const int row0 = mT * 256 + mh * 128 + wm * 64 + fi * 16 + hi * 4;       \
      _Pragma("unroll") for (int nh = 0; nh < 2; ++nh) {                       \
        const int fc = _nT * 128 + (nh * 4 + wn) * 16 + rlo;                   \
        const f32x4 g = acc[mh * 4 + fi][nh * 2 + 0];                          \
        const f32x4 u = acc[mh * 4 + fi][nh * 2 + 1];                          \
        _Pragma("unroll") for (int r = 0; r < 4; ++r) {                        \
          const float gv = g[r];                                               \
          const float hv = gv / (1.f + __expf(-gv)) * u[r];                    \
          H[(size_t)(row0 + r) * 11008 + fc] = f2bf(hv);                       \
        }                                                                      \
      }                                                                        \
    }                                                                          \
  } while (0)

  // prologue: tile0 full -> buf0; tile1 {A-h0, B-h0, B-h1} -> buf1
  PSTG_A(0, 0, 0); PSTG_B(0, 0, 0); PSTG_B(0, 1, 0); PSTG_A(0, 1, 0);
  PSTG_A(1, 0, 1); PSTG_B(1, 0, 1); PSTG_B(1, 1, 1);
  VMCNT6();
  SBAR();

  for (int T = 0; T < FK - 2; T += 2) {
    // P1: af(mh0), bf0 | stage A-h1(T+1)->buf1
    LDA(0, 0); LDBS(0, 0, 0);
    PSTG_A(1, 1, T + 1);
    LGKM8();
    SBAR(); LGKM0(); MFMA16(0, 0); SBAR();
    // P2: bf1 | stage A-h0(T+2)->buf0
    LDBS(1, 0, 1);
    PSTG_A(0, 0, T + 2);
    SBAR(); LGKM0(); MFMA16(0, 1); SBAR();
    // P3: af(mh1) | stage B-h0(T+2)->buf0
    LDA(0, 1);
    PSTG_B(0, 0, T + 2);
    SBAR(); LGKM0(); MFMA16(1, 1); SBAR();
    // P4: no reads | stage B-h1(T+2)->buf0 | checkpoint
    PSTG_B(0, 1, T + 2);
    VMCNT6();
    SBAR(); MFMA16(1, 0); SBAR();
    // P5: buf1 af(mh0), bf0 | stage A-h1(T+2)->buf0
    LDA(1, 0); LDBS(0, 1, 0);
    PSTG_A(0, 1, T + 2);
    LGKM8();
    SBAR(); LGKM0(); MFMA16(0, 0); SBAR();
    // P6: bf1 | stage A-h0(T+3)->buf1
    LDBS(1, 1, 1);
    PSTG_A(1, 0, T + 3);
    SBAR(); LGKM0(); MFMA16(0, 1); SBAR();
    // P7: af(mh1) | stage B-h0(T+3)->buf1
    LDA(1, 1);
    PSTG_B(1, 0, T + 3);
    SBAR(); LGKM0(); MFMA16(1, 1); SBAR();
    // P8: no reads | stage B-h1(T+3)->buf1 | checkpoint
    PSTG_B(1, 1, T + 3);
    VMCNT6();
    SBAR(); MFMA16(1, 0); SBAR();

    if ((T & 63) == 62) {  // tile (T>>6) complete
      GU_EPI(c + 16 * (T >> 6));
#pragma unroll
      for (int i = 0; i < 8; ++i)
#pragma unroll
        for (int j = 0; j < 4; ++j) acc[i][j] = z;
    }
    if ((T & 7) == 6) {  // pace the 8 B-panel sharers every 8 K-tiles
      if (t == 0) {
        int* p = pacecnt + gid * 48 + (T >> 3);
        __hip_atomic_fetch_add(p, 1, __ATOMIC_RELAXED,
                               __HIP_MEMORY_SCOPE_AGENT);
        int itc = 0;
        while (__hip_atomic_load(p, __ATOMIC_RELAXED,
                                 __HIP_MEMORY_SCOPE_AGENT) < 8 &&
               ++itc < (1 << 20)) {}
      }
      SBAR();  // raw barrier: control-sync only, keeps vmcnt pipeline intact
    }
  }
  // tail pair (tiles FK-2, FK-1): P1 stages the last half; drain at P4
  {
    LDA(0, 0); LDBS(0, 0, 0);
    PSTG_A(1, 1, FK - 1);
    LGKM8();
    SBAR(); LGKM0(); MFMA16(0, 0); SBAR();
    LDBS(1, 0, 1);
    SBAR(); LGKM0(); MFMA16(0, 1); SBAR();
    LDA(0, 1);
    SBAR(); LGKM0(); MFMA16(1, 1); SBAR();
    VMCNT0();
    SBAR(); MFMA16(1, 0); SBAR();
    LDA(1, 0); LDBS(0, 1, 0);
    LGKM8();
    SBAR(); LGKM0(); MFMA16(0, 0); SBAR();
    LDBS(1, 1, 1);
    SBAR(); LGKM0(); MFMA16(0, 1); SBAR();
    LDA(1, 1);
    SBAR(); LGKM0(); MFMA16(1, 1); SBAR();
    MFMA16(1, 0);
  }
  GU_EPI(c + 16 * (ntiles - 1));
#undef PSTG_A
#undef PSTG_B
#undef LDA
#undef LDBS
#undef MFMA16
#undef GU_EPI
}

// ---------------- down GEMM (frag-once schedule, single tile) --------------
__global__ __launch_bounds__(512, 1) void gemm_down(
    const u16* __restrict__ A, const u16* __restrict__ Bl,
    const u16* __restrict__ Bv, const int* __restrict__ tt,
    float* __restrict__ O) {
  constexpr int KB = 22016;
  constexpr int NK = KB / 128;  // 172
  __shared__ u16 sA[2][2][128][64];
  __shared__ u16 sB[2][2][128][64];

  const int bid = blockIdx.x;
  const int wg = (bid & 7) * 32 + (bid >> 3);
  const int mT = wg & 15;
  const int nT = wg >> 4;

  const int t = threadIdx.x;
  const int lane = t & 63;
  const int rlo = lane & 15;
  const int hi = lane >> 4;
  const int wn = (t >> 6) & 3;
  const int wm = (t >> 8) & 1;

  const int side = tt[mT << 8];
  const u16* B = side ? Bl : Bv;

  const int rowq = t >> 3;
  const int gsw = ((t & 7) ^ (rowq & 7)) << 4;
  const char* srcA = (const char*)A + (size_t)(mT * 256 + rowq) * KB + gsw;
  const char* srcB = (const char*)B + (size_t)(nT * 256 + rowq) * KB + gsw;
  char* ldsA = (char*)&sA[0][0][0][0];
  char* ldsB = (char*)&sB[0][0][0][0];
  const int woff = (t & 448) << 4;

#define STG_A(d, h, kt)                                                        \
  do {                                                                         \
    GLOAD16(srcA + (size_t)((h) * 128) * KB + (kt) * 128,                      \
            ldsA + (d) * 32768 + (h) * 16384 + woff);                          \
    GLOAD16(srcA + (size_t)((h) * 128 + 64) * KB + (kt) * 128,                 \
            ldsA + (d) * 32768 + (h) * 16384 + 8192 + woff);                   \
  } while (0)
#define STG_B(d, h, kt)                                                        \
  do {                                                                         \
    GLOAD16(srcB + (size_t)((h) * 128) * KB + (kt) * 128,                      \
            ldsB + (d) * 32768 + (h) * 16384 + woff);                          \
    GLOAD16(srcB + (size_t)((h) * 128 + 64) * KB + (kt) * 128,                 \
            ldsB + (d) * 32768 + (h) * 16384 + 8192 + woff);                   \
  } while (0)

  const int cxa = (hi ^ (rlo & 7)) << 4;
  const int cxb = ((4 + hi) ^ (rlo & 7)) << 4;
  const int arow = (wm * 64 + rlo) * 128;
  const int brow = (wn * 32 + rlo) * 128;

  s16x8 af[4][2], bf[2][2][2];
  f32x4 acc[8][4];
  const f32x4 z = {0.f, 0.f, 0.f, 0.f};
#pragma unroll
  for (int i = 0; i < 8; ++i)
#pragma unroll
    for (int j = 0; j < 4; ++j) acc[i][j] = z;

#define LDA(d, mh)                                                             \
  do {                                                                         \
    _Pragma("unroll") for (int fi = 0; fi < 4; ++fi) {                         \
      const char* p = ldsA + (d) * 32768 + (mh) * 16384 + arow + fi * 2048;    \
      af[fi][0] = *(const s16x8*)(p + cxa);                                    \
      af[fi][1] = *(const s16x8*)(p + cxb);                                    \
    }                                                                          \
  } while (0)
#define LDBS(bi, d, nh)                                                        \
  do {                                                                         \
    _Pragma("unroll") for (int gi = 0; gi < 2; ++gi) {                         \
      const char* p = ldsB + (d) * 32768 + (nh) * 16384 + brow + gi * 2048;    \
      bf[bi][gi][0] = *(const s16x8*)(p + cxa);                                \
      bf[bi][gi][1] = *(const s16x8*)(p + cxb);                                \
    }                                                                          \
  } while (0)
#define MFMA16(mh, nh)                                                         \
  do {                                                                         \
    __builtin_amdgcn_s_setprio(1);                                             \
    _Pragma("unroll") for (int fi = 0; fi < 4; ++fi)                           \
        _Pragma("unroll") for (int gi = 0; gi < 2; ++gi) {                     \
      acc[(mh)*4 + fi][(nh)*2 + gi] = __builtin_amdgcn_mfma_f32_16x16x32_bf16( \
          af[fi][0], bf[nh][gi][0], acc[(mh)*4 + fi][(nh)*2 + gi], 0, 0, 0);   \
      acc[(mh)*4 + fi][(nh)*2 + gi] = __builtin_amdgcn_mfma_f32_16x16x32_bf16( \
          af[fi][1], bf[nh][gi][1], acc[(mh)*4 + fi][(nh)*2 + gi], 0, 0, 0);   \
    }                                                                          \
    __builtin_amdgcn_s_setprio(0);                                             \
  } while (0)

  STG_A(0, 0, 0); STG_B(0, 0, 0); STG_B(0, 1, 0); STG_A(0, 1, 0);
  STG_A(1, 0, 1); STG_B(1, 0, 1); STG_B(1, 1, 1);
  VMCNT6();
  SBAR();

  for (int T = 0; T < NK - 2; T += 2) {
    LDA(0, 0); LDBS(0, 0, 0);
    STG_A(1, 1, T + 1);
    LGKM8();
    SBAR(); LGKM0(); MFMA16(0, 0); SBAR();
    LDBS(1, 0, 1);
    STG_A(0, 0, T + 2);
    SBAR(); LGKM0(); MFMA16(0, 1); SBAR();
    LDA(0, 1);
    STG_B(0, 0, T + 2);
    SBAR(); LGKM0(); MFMA16(1, 1); SBAR();
    STG_B(0, 1, T + 2);
    VMCNT6();
    SBAR(); MFMA16(1, 0); SBAR();
    LDA(1, 0); LDBS(0, 1, 0);
    STG_A(0, 1, T + 2);
    LGKM8();
    SBAR(); LGKM0(); MFMA16(0, 0); SBAR();
    LDBS(1, 1, 1);
    STG_A(1, 0, T + 3);
    SBAR(); LGKM0(); MFMA16(0, 1); SBAR();
    LDA(1, 1);
    STG_B(1, 0, T + 3);
    SBAR(); LGKM0(); MFMA16(1, 1); SBAR();
    STG_B(1, 1, T + 3);
    VMCNT6();
    SBAR(); MFMA16(1, 0); SBAR();
  }
  {
    LDA(0, 0); LDBS(0, 0, 0);
    STG_A(1, 1, NK - 1);
    LGKM8();
    SBAR(); LGKM0(); MFMA16(0, 0); SBAR();
    LDBS(1, 0, 1);
    SBAR(); LGKM0(); MFMA16(0, 1); SBAR();
    LDA(0, 1);
    SBAR(); LGKM0(); MFMA16(1, 1); SBAR();
    VMCNT0();
    SBAR(); MFMA16(1, 0); SBAR();
    LDA(1, 0); LDBS(0, 1, 0);
    LGKM8();
    SBAR(); LGKM0(); MFMA16(0, 0); SBAR();
    LDBS(1, 1, 1);
    SBAR(); LGKM0(); MFMA16(0, 1); SBAR();
    LDA(1, 1);
    SBAR(); LGKM0(); MFMA16(1, 1); SBAR();
    MFMA16(1, 0);
  }

#pragma unroll
  for (int mh = 0; mh < 2; ++mh)
#pragma unroll
    for (int fi = 0; fi < 4; ++fi) {
      const int row0 = mT * 256 + mh * 128 + wm * 64 + fi * 16 + hi * 4;
#pragma unroll
      for (int nh = 0; nh < 2; ++nh)
#pragma unroll
        for (int gi = 0; gi < 2; ++gi) {
          const int col = nT * 256 + nh * 128 + wn * 32 + gi * 16 + rlo;
          const f32x4 a = acc[mh * 4 + fi][nh * 2 + gi];
#pragma unroll
          for (int r = 0; r < 4; ++r)
            O[(size_t)(row0 + r) * 4096 + col] = a[r];
        }
    }
#undef STG_A
#undef STG_B
#undef LDA
#undef LDBS
#undef MFMA16
}

extern "C" void kernel_launch(void* const* d_in, const int* in_sizes, int n_in,
                              void* d_out, int out_size, void* d_ws, size_t ws_size,
                              hipStream_t stream) {
  (void)in_sizes; (void)n_in; (void)out_size; (void)ws_size;
  const float* x  = (const float*)d_in[0];
  const int*   tt = (const int*)d_in[1];
  const float* lg = (const float*)d_in[2];
  const float* lu = (const float*)d_in[3];
  const float* ld = (const float*)d_in[4];
  const float* vg = (const float*)d_in[5];
  const float* vu = (const float*)d_in[6];
  const float* vd = (const float*)d_in[7];

  u16* ws  = (u16*)d_ws;
  u16* xbf = ws;                        // 4096*4096            = 16,777,216
  u16* GUl = xbf + 16777216;            // 22016*4096           = 90,177,536
  u16* GUv = GUl + 90177536;
  u16* ldT = GUv + 90177536;            // 4096*11008           = 45,088,768
  u16* vdT = ldT + 45088768;
  u16* hbuf = vdT + 45088768;           // 4096*11008
  int* pacecnt = (int*)(hbuf + 45088768);  // 32 groups x 48 slots
  // total: ~665 MB + 6 KB

  hipMemsetAsync(pacecnt, 0, 32 * 48 * sizeof(int), stream);
  prep_kernel<<<dim3(11008, 7), dim3(256), 0, stream>>>(
      lg, lu, vg, vu, ld, vd, x, GUl, GUv, ldT, vdT, xbf);
  gemm_gateup_persist<<<dim3(256), dim3(512), 0, stream>>>(
      xbf, GUl, GUv, tt, hbuf, pacecnt);
  gemm_down<<<dim3(256), dim3(512), 0, stream>>>(hbuf, ldT, vdT, tt, (float*)d_out);
}

// Round 12
// 1313.702 us; speedup vs baseline: 1.0098x; 1.0098x over previous
//
#include <hip/hip_runtime.h>
#include <math.h>

typedef unsigned short u16;
typedef short s16x8 __attribute__((ext_vector_type(8)));
typedef float f32x4 __attribute__((ext_vector_type(4)));

#define GLOAD16(gp, lp)                                                        \
  __builtin_amdgcn_global_load_lds(                                            \
      (const __attribute__((address_space(1))) void*)(gp),                     \
      (__attribute__((address_space(3))) void*)(lp), 16, 0, 0)

__device__ __forceinline__ u16 f2bf(float f) {
  union { float f; unsigned u; } v; v.f = f;
  unsigned r = v.u + 0x7fffu + ((v.u >> 16) & 1u);  // RNE
  return (u16)(r >> 16);
}

// ------- kernel A: transpose+cvt (y=0..5) + x cvt (y=6).
// mats 0-3 (g/u) write into interleaved GU: row = (f>>4)*32 + t*16 + (f&15).
// mats 4,5 plain transpose. y=6: x fp32->bf16 flat copy (blocks 0..8191).
__global__ __launch_bounds__(256) void prep_kernel(
    const float* __restrict__ in0, const float* __restrict__ in1,
    const float* __restrict__ in2, const float* __restrict__ in3,
    const float* __restrict__ in4, const float* __restrict__ in5,
    const float* __restrict__ xin,
    u16* __restrict__ o01, u16* __restrict__ o23,
    u16* __restrict__ o4, u16* __restrict__ o5, u16* __restrict__ xout) {
  const int mat = blockIdx.y;
  const int t = threadIdx.x;
  if (mat == 6) {  // x conversion: 8192 blocks x 2048 elems
    if (blockIdx.x >= 8192) return;
    size_t i = ((size_t)blockIdx.x * 256 + t) * 8;
    float4 a = *(const float4*)(xin + i);
    float4 b = *(const float4*)(xin + i + 4);
    s16x8 v;
    v[0] = (short)f2bf(a.x); v[1] = (short)f2bf(a.y);
    v[2] = (short)f2bf(a.z); v[3] = (short)f2bf(a.w);
    v[4] = (short)f2bf(b.x); v[5] = (short)f2bf(b.y);
    v[6] = (short)f2bf(b.z); v[7] = (short)f2bf(b.w);
    *(s16x8*)(xout + i) = v;
    return;
  }
  __shared__ float s[64 * 65];
  const float* in; u16* out;
  switch (mat) {
    case 0: in = in0; out = o01; break;
    case 1: in = in1; out = o01; break;
    case 2: in = in2; out = o23; break;
    case 3: in = in3; out = o23; break;
    case 4: in = in4; out = o4; break;
    default: in = in5; out = o5; break;
  }
  const int R = (mat < 4) ? 4096 : 11008;   // input rows = output stride
  const int C = (mat < 4) ? 11008 : 4096;   // input cols
  const int nTc = C >> 6;
  const int tr = blockIdx.x / nTc, tc = blockIdx.x - tr * nTc;
  const int r0 = tr << 6, c0 = tc << 6;
#pragma unroll
  for (int p = 0; p < 4; ++p) {
    const int lr = p * 16 + (t >> 4);
    const int lc = (t & 15) * 4;
    float4 v = *(const float4*)(in + (size_t)(r0 + lr) * C + (c0 + lc));
    float* sp = &s[lr * 65 + lc];
    sp[0] = v.x; sp[1] = v.y; sp[2] = v.z; sp[3] = v.w;
  }
  __syncthreads();
#pragma unroll
  for (int q = 0; q < 2; ++q) {
    const int oc = q * 32 + (t >> 3);
    const int orr = (t & 7) * 8;
    s16x8 v;
#pragma unroll
    for (int i = 0; i < 8; ++i) v[i] = (short)f2bf(s[(orr + i) * 65 + oc]);
    const int f = c0 + oc;
    size_t orow;
    if (mat < 4) orow = (size_t)((f >> 4) << 5) + ((mat & 1) << 4) + (f & 15);
    else         orow = (size_t)f;
    *(s16x8*)(out + orow * R + (r0 + orr)) = v;
  }
}

// ======== 8-phase 256x256 GEMM, frag-once schedule (R5 core, verified) ======
#define SBAR() __builtin_amdgcn_s_barrier()
#define LGKM0() asm volatile("s_waitcnt lgkmcnt(0)")
#define LGKM8() asm volatile("s_waitcnt lgkmcnt(8)")
#define VMCNT6() asm volatile("s_waitcnt vmcnt(6)")
#define VMCNT0() asm volatile("s_waitcnt vmcnt(0)")

// ---------------- gate+up GEMM + silu fusion, atomic work queue -------------
// Queue completes the 2x2 factorial: R5's verified frag-once 16x16 8-phase
// core + R7's verified queue wrapper (adapts tile placement to realized
// per-XCD speed; removes the static map's rigidity). Pop order n-major:
// 16 consecutive pops share one B panel.
__global__ __launch_bounds__(512, 1) void gemm_gateup_queue(
    const u16* __restrict__ A, const u16* __restrict__ Bl,
    const u16* __restrict__ Bv, const int* __restrict__ tt,
    u16* __restrict__ H, int* __restrict__ qcnt) {
  __shared__ u16 sA[2][2][128][64];
  __shared__ u16 sB[2][2][128][64];
  __shared__ int sQ;

  const int t = threadIdx.x;
  const int lane = t & 63;
  const int rlo = lane & 15;
  const int hi = lane >> 4;
  const int wn = (t >> 6) & 3;
  const int wm = (t >> 8) & 1;

  const int rowq = t >> 3;
  const int gsw = ((t & 7) ^ (rowq & 7)) << 4;
  char* ldsA = (char*)&sA[0][0][0][0];
  char* ldsB = (char*)&sB[0][0][0][0];
  const int woff = (t & 448) << 4;

  const int cxa = (hi ^ (rlo & 7)) << 4;
  const int cxb = ((4 + hi) ^ (rlo & 7)) << 4;
  const int arow = (wm * 64 + rlo) * 128;
  const int brow = (wn * 32 + rlo) * 128;

  s16x8 af[4][2], bf[2][2][2];  // bf[nh-set][gi][ks] resident across P1..P4
  f32x4 acc[8][4];
  const f32x4 z = {0.f, 0.f, 0.f, 0.f};

#define QSTG_A(d, h, kt)                                                       \
  do {                                                                         \
    GLOAD16(srcA + (size_t)((h) * 128) * 8192 + (kt) * 128,                    \
            ldsA + (d) * 32768 + (h) * 16384 + woff);                          \
    GLOAD16(srcA + (size_t)((h) * 128 + 64) * 8192 + (kt) * 128,               \
            ldsA + (d) * 32768 + (h) * 16384 + 8192 + woff);                   \
  } while (0)
#define QSTG_B(d, h, kt)                                                       \
  do {                                                                         \
    GLOAD16(srcB + (size_t)((h) * 128) * 8192 + (kt) * 128,                    \
            ldsB + (d) * 32768 + (h) * 16384 + woff);                          \
    GLOAD16(srcB + (size_t)((h) * 128 + 64) * 8192 + (kt) * 128,               \
            ldsB + (d) * 32768 + (h) * 16384 + 8192 + woff);                   \
  } while (0)
#define LDA(d, mh)                                                             \
  do {                                                                         \
    _Pragma("unroll") for (int fi = 0; fi < 4; ++fi) {                         \
      const char* p = ldsA + (d) * 32768 + (mh) * 16384 + arow + fi * 2048;    \
      af[fi][0] = *(const s16x8*)(p + cxa);                                    \
      af[fi][1] = *(const s16x8*)(p + cxb);                                    \
    }                                                                          \
  } while (0)
#define LDBS(bi, d, nh)                                                        \
  do {                                                                         \
    _Pragma("unroll") for (int gi = 0; gi < 2; ++gi) {                         \
      const char* p = ldsB + (d) * 32768 + (nh) * 16384 + brow + gi * 2048;    \
      bf[bi][gi][0] = *(const s16x8*)(p + cxa);                                \
      bf[bi][gi][1] = *(const s16x8*)(p + cxb);                                \
    }                                                                          \
  } while (0)
#define MFMA16(mh, nh)                                                         \
  do {                                                                         \
    __builtin_amdgcn_s_setprio(1);                                             \
    _Pragma("unroll") for (int fi = 0; fi < 4; ++fi)                           \
        _Pragma("unroll") for (int gi = 0; gi < 2; ++gi) {                     \
      acc[(mh)*4 + fi][(nh)*2 + gi] = __builtin_amdgcn_mfma_f32_16x16x32_bf16( \
          af[fi][0], bf[nh][gi][0], acc[(mh)*4 + fi][(nh)*2 + gi], 0, 0, 0);   \
      acc[(mh)*4 + fi][(nh)*2 + gi] = __builtin_amdgcn_mfma_f32_16x16x32_bf16( \
          af[fi][1], bf[nh][gi][1], acc[(mh)*4 + fi][(nh)*2 + gi], 0, 0, 0);   \
    }                                                                          \
    __builtin_amdgcn_s_setprio(0);                                             \
  } while (0)

  for (;;) {
    __syncthreads();
    if (t == 0) sQ = atomicAdd(qcnt, 1);
    __syncthreads();
    const int q = sQ;
    if (q >= 1376) break;
    const int nT = q >> 4;
    const int mT = q & 15;
    const int side = tt[mT << 8];
    const u16* GU = side ? Bl : Bv;
    const char* srcA = (const char*)A + (size_t)(mT * 256 + rowq) * 8192 + gsw;
    const char* srcB = (const char*)GU + (size_t)(nT * 256 + rowq) * 8192 + gsw;

#pragma unroll
    for (int i = 0; i < 8; ++i)
#pragma unroll
      for (int j = 0; j < 4; ++j) acc[i][j] = z;

    // prologue: tile0 full -> buf0; tile1 {A-h0, B-h0, B-h1} -> buf1
    QSTG_A(0, 0, 0); QSTG_B(0, 0, 0); QSTG_B(0, 1, 0); QSTG_A(0, 1, 0);
    QSTG_A(1, 0, 1); QSTG_B(1, 0, 1); QSTG_B(1, 1, 1);
    VMCNT6();
    SBAR();

    for (int T = 0; T < 62; T += 2) {
      // P1: af(mh0), bf0 | stage A-h1(T+1)->buf1
      LDA(0, 0); LDBS(0, 0, 0);
      QSTG_A(1, 1, T + 1);
      LGKM8();
      SBAR(); LGKM0(); MFMA16(0, 0); SBAR();
      // P2: bf1 | stage A-h0(T+2)->buf0
      LDBS(1, 0, 1);
      QSTG_A(0, 0, T + 2);
      SBAR(); LGKM0(); MFMA16(0, 1); SBAR();
      // P3: af(mh1) | stage B-h0(T+2)->buf0
      LDA(0, 1);
      QSTG_B(0, 0, T + 2);
      SBAR(); LGKM0(); MFMA16(1, 1); SBAR();
      // P4: no reads | stage B-h1(T+2)->buf0 | checkpoint
      QSTG_B(0, 1, T + 2);
      VMCNT6();
      SBAR(); MFMA16(1, 0); SBAR();
      // P5: buf1 af(mh0), bf0 | stage A-h1(T+2)->buf0
      LDA(1, 0); LDBS(0, 1, 0);
      QSTG_A(0, 1, T + 2);
      LGKM8();
      SBAR(); LGKM0(); MFMA16(0, 0); SBAR();
      // P6: bf1 | stage A-h0(T+3)->buf1
      LDBS(1, 1, 1);
      QSTG_A(1, 0, T + 3);
      SBAR(); LGKM0(); MFMA16(0, 1); SBAR();
      // P7: af(mh1) | stage B-h0(T+3)->buf1
      LDA(1, 1);
      QSTG_B(1, 0, T + 3);
      SBAR(); LGKM0(); MFMA16(1, 1); SBAR();
      // P8: no reads | stage B-h1(T+3)->buf1 | checkpoint
      QSTG_B(1, 1, T + 3);
      VMCNT6();
      SBAR(); MFMA16(1, 0); SBAR();
    }
    // tail pair (K-tiles 62, 63): P1 stages the last half; drain at P4
    {
      LDA(0, 0); LDBS(0, 0, 0);
      QSTG_A(1, 1, 63);
      LGKM8();
      SBAR(); LGKM0(); MFMA16(0, 0); SBAR();
      LDBS(1, 0, 1);
      SBAR(); LGKM0(); MFMA16(0, 1); SBAR();
      LDA(0, 1);
      SBAR(); LGKM0(); MFMA16(1, 1); SBAR();
      VMCNT0();
      SBAR(); MFMA16(1, 0); SBAR();
      LDA(1, 0); LDBS(0, 1, 0);
      LGKM8();
      SBAR(); LGKM0(); MFMA16(0, 0); SBAR();
      LDBS(1, 1, 1);
      SBAR(); LGKM0(); MFMA16(0, 1); SBAR();
      LDA(1, 1);
      SBAR(); LGKM0(); MFMA16(1, 1); SBAR();
      MFMA16(1, 0);
    }

    // epilogue: silu(gate)*up -> H
#pragma unroll
    for (int mh = 0; mh < 2; ++mh)
#pragma unroll
      for (int fi = 0; fi < 4; ++fi) {
        const int row0 = mT * 256 + mh * 128 + wm * 64 + fi * 16 + hi * 4;
#pragma unroll
        for (int nh = 0; nh < 2; ++nh) {
          const int fc = nT * 128 + (nh * 4 + wn) * 16 + rlo;
          const f32x4 g = acc[mh * 4 + fi][nh * 2 + 0];
          const f32x4 u = acc[mh * 4 + fi][nh * 2 + 1];
#pragma unroll
          for (int r = 0; r < 4; ++r) {
            const float gv = g[r];
            const float hv = gv / (1.f + __expf(-gv)) * u[r];
            H[(size_t)(row0 + r) * 11008 + fc] = f2bf(hv);
          }
        }
      }
  }
#undef QSTG_A
#undef QSTG_B
#undef LDA
#undef LDBS
#undef MFMA16
}

// ---------------- down GEMM (frag-once schedule, single tile) --------------
__global__ __launch_bounds__(512, 1) void gemm_down(
    const u16* __restrict__ A, const u16* __restrict__ Bl,
    const u16* __restrict__ Bv, const int* __restrict__ tt,
    float* __restrict__ O) {
  constexpr int KB = 22016;
  constexpr int NK = KB / 128;  // 172
  __shared__ u16 sA[2][2][128][64];
  __shared__ u16 sB[2][2][128][64];

  const int bid = blockIdx.x;
  const int wg = (bid & 7) * 32 + (bid >> 3);
  const int mT = wg & 15;
  const int nT = wg >> 4;

  const int t = threadIdx.x;
  const int lane = t & 63;
  const int rlo = lane & 15;
  const int hi = lane >> 4;
  const int wn = (t >> 6) & 3;
  const int wm = (t >> 8) & 1;

  const int side = tt[mT << 8];
  const u16* B = side ? Bl : Bv;

  const int rowq = t >> 3;
  const int gsw = ((t & 7) ^ (rowq & 7)) << 4;
  const char* srcA = (const char*)A + (size_t)(mT * 256 + rowq) * KB + gsw;
  const char* srcB = (const char*)B + (size_t)(nT * 256 + rowq) * KB + gsw;
  char* ldsA = (char*)&sA[0][0][0][0];
  char* ldsB = (char*)&sB[0][0][0][0];
  const int woff = (t & 448) << 4;

#define STG_A(d, h, kt)                                                        \
  do {                                                                         \
    GLOAD16(srcA + (size_t)((h) * 128) * KB + (kt) * 128,                      \
            ldsA + (d) * 32768 + (h) * 16384 + woff);                          \
    GLOAD16(srcA + (size_t)((h) * 128 + 64) * KB + (kt) * 128,                 \
            ldsA + (d) * 32768 + (h) * 16384 + 8192 + woff);                   \
  } while (0)
#define STG_B(d, h, kt)                                                        \
  do {                                                                         \
    GLOAD16(srcB + (size_t)((h) * 128) * KB + (kt) * 128,                      \
            ldsB + (d) * 32768 + (h) * 16384 + woff);                          \
    GLOAD16(srcB + (size_t)((h) * 128 + 64) * KB + (kt) * 128,                 \
            ldsB + (d) * 32768 + (h) * 16384 + 8192 + woff);                   \
  } while (0)

  const int cxa = (hi ^ (rlo & 7)) << 4;
  const int cxb = ((4 + hi) ^ (rlo & 7)) << 4;
  const int arow = (wm * 64 + rlo) * 128;
  const int brow = (wn * 32 + rlo) * 128;

  s16x8 af[4][2], bf[2][2][2];
  f32x4 acc[8][4];
  const f32x4 z = {0.f, 0.f, 0.f, 0.f};
#pragma unroll
  for (int i = 0; i < 8; ++i)
#pragma unroll
    for (int j = 0; j < 4; ++j) acc[i][j] = z;

#define LDA(d, mh)                                                             \
  do {                                                                         \
    _Pragma("unroll") for (int fi = 0; fi < 4; ++fi) {                         \
      const char* p = ldsA + (d) * 32768 + (mh) * 16384 + arow + fi * 2048;    \
      af[fi][0] = *(const s16x8*)(p + cxa);                                    \
      af[fi][1] = *(const s16x8*)(p + cxb);                                    \
    }                                                                          \
  } while (0)
#define LDBS(bi, d, nh)                                                        \
  do {                                                                         \
    _Pragma("unroll") for (int gi = 0; gi < 2; ++gi) {                         \
      const char* p = ldsB + (d) * 32768 + (nh) * 16384 + brow + gi * 2048;    \
      bf[bi][gi][0] = *(const s16x8*)(p + cxa);                                \
      bf[bi][gi][1] = *(const s16x8*)(p + cxb);                                \
    }                                                                          \
  } while (0)
#define MFMA16(mh, nh)                                                         \
  do {                                                                         \
    __builtin_amdgcn_s_setprio(1);                                             \
    _Pragma("unroll") for (int fi = 0; fi < 4; ++fi)                           \
        _Pragma("unroll") for (int gi = 0; gi < 2; ++gi) {                     \
      acc[(mh)*4 + fi][(nh)*2 + gi] = __builtin_amdgcn_mfma_f32_16x16x32_bf16( \
          af[fi][0], bf[nh][gi][0], acc[(mh)*4 + fi][(nh)*2 + gi], 0, 0, 0);   \
      acc[(mh)*4 + fi][(nh)*2 + gi] = __builtin_amdgcn_mfma_f32_16x16x32_bf16( \
          af[fi][1], bf[nh][gi][1], acc[(mh)*4 + fi][(nh)*2 + gi], 0, 0, 0);   \
    }                                                                          \
    __builtin_amdgcn_s_setprio(0);                                             \
  } while (0)

  STG_A(0, 0, 0); STG_B(0, 0, 0); STG_B(0, 1, 0); STG_A(0, 1, 0);
  STG_A(1, 0, 1); STG_B(1, 0, 1); STG_B(1, 1, 1);
  VMCNT6();
  SBAR();

  for (int T = 0; T < NK - 2; T += 2) {
    LDA(0, 0); LDBS(0, 0, 0);
    STG_A(1, 1, T + 1);
    LGKM8();
    SBAR(); LGKM0(); MFMA16(0, 0); SBAR();
    LDBS(1, 0, 1);
    STG_A(0, 0, T + 2);
    SBAR(); LGKM0(); MFMA16(0, 1); SBAR();
    LDA(0, 1);
    STG_B(0, 0, T + 2);
    SBAR(); LGKM0(); MFMA16(1, 1); SBAR();
    STG_B(0, 1, T + 2);
    VMCNT6();
    SBAR(); MFMA16(1, 0); SBAR();
    LDA(1, 0); LDBS(0, 1, 0);
    STG_A(0, 1, T + 2);
    LGKM8();
    SBAR(); LGKM0(); MFMA16(0, 0); SBAR();
    LDBS(1, 1, 1);
    STG_A(1, 0, T + 3);
    SBAR(); LGKM0(); MFMA16(0, 1); SBAR();
    LDA(1, 1);
    STG_B(1, 0, T + 3);
    SBAR(); LGKM0(); MFMA16(1, 1); SBAR();
    STG_B(1, 1, T + 3);
    VMCNT6();
    SBAR(); MFMA16(1, 0); SBAR();
  }
  {
    LDA(0, 0); LDBS(0, 0, 0);
    STG_A(1, 1, NK - 1);
    LGKM8();
    SBAR(); LGKM0(); MFMA16(0, 0); SBAR();
    LDBS(1, 0, 1);
    SBAR(); LGKM0(); MFMA16(0, 1); SBAR();
    LDA(0, 1);
    SBAR(); LGKM0(); MFMA16(1, 1); SBAR();
    VMCNT0();
    SBAR(); MFMA16(1, 0); SBAR();
    LDA(1, 0); LDBS(0, 1, 0);
    LGKM8();
    SBAR(); LGKM0(); MFMA16(0, 0); SBAR();
    LDBS(1, 1, 1);
    SBAR(); LGKM0(); MFMA16(0, 1); SBAR();
    LDA(1, 1);
    SBAR(); LGKM0(); MFMA16(1, 1); SBAR();
    MFMA16(1, 0);
  }

#pragma unroll
  for (int mh = 0; mh < 2; ++mh)
#pragma unroll
    for (int fi = 0; fi < 4; ++fi) {
      const int row0 = mT * 256 + mh * 128 + wm * 64 + fi * 16 + hi * 4;
#pragma unroll
      for (int nh = 0; nh < 2; ++nh)
#pragma unroll
        for (int gi = 0; gi < 2; ++gi) {
          const int col = nT * 256 + nh * 128 + wn * 32 + gi * 16 + rlo;
          const f32x4 a = acc[mh * 4 + fi][nh * 2 + gi];
#pragma unroll
          for (int r = 0; r < 4; ++r)
            O[(size_t)(row0 + r) * 4096 + col] = a[r];
        }
    }
#undef STG_A
#undef STG_B
#undef LDA
#undef LDBS
#undef MFMA16
}

extern "C" void kernel_launch(void* const* d_in, const int* in_sizes, int n_in,
                              void* d_out, int out_size, void* d_ws, size_t ws_size,
                              hipStream_t stream) {
  (void)in_sizes; (void)n_in; (void)out_size; (void)ws_size;
  const float* x  = (const float*)d_in[0];
  const int*   tt = (const int*)d_in[1];
  const float* lg = (const float*)d_in[2];
  const float* lu = (const float*)d_in[3];
  const float* ld = (const float*)d_in[4];
  const float* vg = (const float*)d_in[5];
  const float* vu = (const float*)d_in[6];
  const float* vd = (const float*)d_in[7];

  u16* ws  = (u16*)d_ws;
  u16* xbf = ws;                        // 4096*4096            = 16,777,216
  u16* GUl = xbf + 16777216;            // 22016*4096           = 90,177,536
  u16* GUv = GUl + 90177536;
  u16* ldT = GUv + 90177536;            // 4096*11008           = 45,088,768
  u16* vdT = ldT + 45088768;
  u16* hbuf = vdT + 45088768;           // 4096*11008
  int* qcnt = (int*)(hbuf + 45088768);  // 4-byte work-queue counter
  // total: ~665 MB + 4 B

  hipMemsetAsync(qcnt, 0, 4, stream);
  prep_kernel<<<dim3(11008, 7), dim3(256), 0, stream>>>(
      lg, lu, vg, vu, ld, vd, x, GUl, GUv, ldT, vdT, xbf);
  gemm_gateup_queue<<<dim3(256), dim3(512), 0, stream>>>(
      xbf, GUl, GUv, tt, hbuf, qcnt);
  gemm_down<<<dim3(256), dim3(512), 0, stream>>>(hbuf, ldT, vdT, tt, (float*)d_out);
}